// Round 20
// baseline (173.674 us; speedup 1.0000x reference)
//
#include <hip/hip_runtime.h>
#include <math.h>

#define N_NODES 50000
#define N_EDGES 800000
#define IN_C    128
#define H_C     128
#define OUT_C   64
#define BCAP    64          // fixed bucket capacity (P(deg>64) ~ 1e-17 for Poisson(16))
#define EPB     2048        // edges per sort chunk
#define CSTRIDE 16          // cursor padded to one 64 B line per node (sort atomics)

typedef unsigned char  u8;
typedef unsigned short u16;
typedef unsigned int   u32;

// bf16 helpers (RNE)
__device__ __forceinline__ u16 f2bf(float f) {
    u32 u; __builtin_memcpy(&u, &f, 4);
    u += 0x7FFFu + ((u >> 16) & 1u);
    return (u16)(u >> 16);
}
__device__ __forceinline__ float bflo(u32 p) { u32 u = p << 16;         float f; __builtin_memcpy(&f, &u, 4); return f; }
__device__ __forceinline__ float bfhi(u32 p) { u32 u = p & 0xFFFF0000u; float f; __builtin_memcpy(&f, &u, 4); return f; }

// decode uint4 = 8 bf16 and accumulate into a[0..7]
__device__ __forceinline__ void acc8(float* a, uint4 p) {
    a[0] += bflo(p.x); a[1] += bfhi(p.x);
    a[2] += bflo(p.y); a[3] += bfhi(p.y);
    a[4] += bflo(p.z); a[5] += bfhi(p.z);
    a[6] += bflo(p.w); a[7] += bfhi(p.w);
}
// decode uint2 = 4 bf16 and accumulate into a[0..3]
__device__ __forceinline__ void acc4(float* a, uint2 p) {
    a[0] += bflo(p.x); a[1] += bfhi(p.x);
    a[2] += bflo(p.y); a[3] += bfhi(p.y);
}

// ---------------------------------------------------------------------------
// edge_index dtype detection (wave-parallel): int64 buffers have all odd
// int32 words == 0 (values < 50000). flag: 1 = int64, 0 = int32.
// ---------------------------------------------------------------------------
__global__ void k_detect_i64(const int* __restrict__ ei, int* __restrict__ flag) {
    int t = threadIdx.x;
    int nz = 0;
    for (int i = t; i < 256; i += 64)
        if (ei[2 * i + 1] != 0) nz = 1;
    unsigned long long b = __ballot(nz != 0);
    if (t == 0) *flag = (b == 0ULL) ? 1 : 0;
}

__device__ __forceinline__ int eidx(const int* __restrict__ ei, size_t pos, int mode) {
    return mode ? ei[pos << 1] : ei[pos];
}

// ---------------------------------------------------------------------------
// merged preprocessing (one 800K-thread kernel):
//   i < 200000: zero the line-padded cursor (int4)
//   i < 16384 : W1 fp32 -> bf16 (32 KB: L1-resident for gemm1's k-loop)
//   i < 800000: compact edge list to u16 (L2-resident for the 8 sort passes)
// ---------------------------------------------------------------------------
__global__ void k_pre(const int* __restrict__ ei, const int* __restrict__ flag,
                      const float* __restrict__ W, u16* __restrict__ Wbf,
                      int4* __restrict__ cursor4,
                      u16* __restrict__ src16, u16* __restrict__ dst16) {
    int i = blockIdx.x * 256 + threadIdx.x;
    if (i < N_NODES * CSTRIDE / 4) cursor4[i] = make_int4(0, 0, 0, 0);
    if (i < IN_C * H_C) Wbf[i] = f2bf(W[i]);
    if (i < N_EDGES) {
        int m = *flag;
        src16[i] = (u16)eidx(ei, (size_t)i, m);
        dst16[i] = (u16)eidx(ei, (size_t)N_EDGES + i, m);
    }
}

// ---------------------------------------------------------------------------
// XCD-partitioned bucket sort over compact u16 edges. Blocks (blockIdx&7)==p
// bin only edges with (dst&7)==p: bucket lines and (line-padded) cursor lines
// are each written by exactly one XCD.
// ---------------------------------------------------------------------------
__global__ void k_sort(const u16* __restrict__ dst16, const u16* __restrict__ src16,
                       int* __restrict__ cursor, u16* __restrict__ sorted_src) {
    const int part = blockIdx.x & 7;
    const int base = (blockIdx.x >> 3) * EPB;
    for (int i = threadIdx.x; i < EPB; i += 256) {
        int e = base + i;
        if (e >= N_EDGES) break;
        int d = dst16[e];
        if ((d & 7) != part) continue;
        int c = atomicAdd(&cursor[(size_t)d << 4], 1);
        if (c < BCAP) sorted_src[((size_t)d << 6) + c] = src16[e];
    }
}

// dinv from counts + dense u8 count array (50 KB, cache-resident for aggs)
__global__ void k_dinv(const int* __restrict__ cursor, float* __restrict__ dinv,
                       u8* __restrict__ cnt8) {
    int i = blockIdx.x * blockDim.x + threadIdx.x;
    if (i < N_NODES) {
        int c = cursor[(size_t)i << 4];
        dinv[i] = rsqrtf((float)c + 1.0f);
        cnt8[i] = (u8)(c > BCAP ? BCAP : c);
    }
}

// ---------------------------------------------------------------------------
// GEMM1: q = dinv .* (x @ W1), fp32 [N][128] -> bf16 row-major [N][128].
// Clone of gemm2's proven barrier-free structure: each wave stages ITS 16
// fp32 rows (8 KB) into a private LDS slice and waits only its own vmcnt --
// no __syncthreads. W1 is read as bf16 DIRECTLY from global: 32 KB = exactly
// L1-sized, so the k-loop's W stream is L1-hit (the old fp32 W was 64 KB =
// 2x L1 -> every read an L2 round-trip; the LDS-W version fixed that but its
// barrier serialized stage/compute at 2 blocks/CU -> 50% gaps).
// 256 threads, 32 KB LDS -> 4 blocks/CU of independent waves.
// ---------------------------------------------------------------------------
__launch_bounds__(256, 4)
__global__ void k_gemm1(const float* __restrict__ X, const u16* __restrict__ Wbf,
                        const float* __restrict__ dinv, u16* __restrict__ outq) {
    __shared__ __align__(16) char xs[32768];    // 4 waves x 8 KB private slices
    const int tid = threadIdx.x, wv = tid >> 6, lane = tid & 63;
    const int row0 = blockIdx.x * 64 + wv * 16;
    const size_t limit = (size_t)N_NODES * 512 - 1024;   // last full 1 KB of x
    const char* Xb = (const char*)X;

#pragma unroll
    for (int chk = 0; chk < 8; ++chk) {          // wave's 16 X rows (8 KB)
        size_t off = (size_t)row0 * 512 + (size_t)chk * 1024;
        if (off > limit) off = limit;            // tail: dup last chunk (store-masked)
        __builtin_amdgcn_global_load_lds(
            (const __attribute__((address_space(1))) void*)(Xb + off + (size_t)lane * 16),
            (__attribute__((address_space(3))) void*)(xs + wv * 8192 + chk * 1024),
            16, 0, 0);
    }
    asm volatile("s_waitcnt vmcnt(0)" ::: "memory");
    __builtin_amdgcn_sched_barrier(0);

    const int c4 = (lane & 31) * 4;   // output channel base (0..124)
    const int rs = lane >> 5;         // row parity (0/1)

    float4 acc[8];
#pragma unroll
    for (int r = 0; r < 8; ++r) acc[r] = make_float4(0.f, 0.f, 0.f, 0.f);

#pragma unroll 2
    for (int k4 = 0; k4 < IN_C / 4; ++k4) {
        float4 xv[8];
#pragma unroll
        for (int r = 0; r < 8; ++r)
            xv[r] = *reinterpret_cast<const float4*>(
                &xs[wv * 8192 + (rs + r * 2) * 512 + k4 * 16]);
        float4 w[4];
#pragma unroll
        for (int r = 0; r < 4; ++r) {
            // W row (4*k4+r), 4 bf16 ch from global (L1-hit: W = 32 KB = L1)
            uint2 wu = *reinterpret_cast<const uint2*>(Wbf + (size_t)(4 * k4 + r) * H_C + c4);
            w[r].x = bflo(wu.x); w[r].y = bfhi(wu.x);
            w[r].z = bflo(wu.y); w[r].w = bfhi(wu.y);
        }
#pragma unroll
        for (int r = 0; r < 8; ++r) {
            acc[r].x = fmaf(xv[r].x, w[0].x, acc[r].x);
            acc[r].y = fmaf(xv[r].x, w[0].y, acc[r].y);
            acc[r].z = fmaf(xv[r].x, w[0].z, acc[r].z);
            acc[r].w = fmaf(xv[r].x, w[0].w, acc[r].w);
            acc[r].x = fmaf(xv[r].y, w[1].x, acc[r].x);
            acc[r].y = fmaf(xv[r].y, w[1].y, acc[r].y);
            acc[r].z = fmaf(xv[r].y, w[1].z, acc[r].z);
            acc[r].w = fmaf(xv[r].y, w[1].w, acc[r].w);
            acc[r].x = fmaf(xv[r].z, w[2].x, acc[r].x);
            acc[r].y = fmaf(xv[r].z, w[2].y, acc[r].y);
            acc[r].z = fmaf(xv[r].z, w[2].z, acc[r].z);
            acc[r].w = fmaf(xv[r].z, w[2].w, acc[r].w);
            acc[r].x = fmaf(xv[r].w, w[3].x, acc[r].x);
            acc[r].y = fmaf(xv[r].w, w[3].y, acc[r].y);
            acc[r].z = fmaf(xv[r].w, w[3].z, acc[r].z);
            acc[r].w = fmaf(xv[r].w, w[3].w, acc[r].w);
        }
    }

#pragma unroll
    for (int r = 0; r < 8; ++r) {
        int row = row0 + rs + r * 2;
        if (row < N_NODES) {
            float di = dinv[row];
            ushort4 o;
            o.x = f2bf(acc[r].x * di);
            o.y = f2bf(acc[r].y * di);
            o.z = f2bf(acc[r].z * di);
            o.w = f2bf(acc[r].w * di);
            *reinterpret_cast<ushort4*>(outq + (size_t)row * H_C + c4) = o;
        }
    }
}

// ---------------------------------------------------------------------------
// GEMM2: p = g @ Wmu, bf16 row-major [N][128] -> bf16 row-major [N][64].
// Wave stages its 32 rows (8 KB bf16) independently; no __syncthreads.
// ---------------------------------------------------------------------------
__launch_bounds__(256, 4)
__global__ void k_gemm2(const u16* __restrict__ gbuf, const float* __restrict__ W,
                        u16* __restrict__ outp) {
    __shared__ __align__(16) char xs[32768];
    const int tid = threadIdx.x, wv = tid >> 6, lane = tid & 63;
    const int row0 = blockIdx.x * 128 + wv * 32;
    const size_t limit = (size_t)N_NODES * 256 - 1024;   // last full 1 KB of g
    const char* Gb = (const char*)gbuf;

#pragma unroll
    for (int chk = 0; chk < 8; ++chk) {
        size_t off = (size_t)row0 * 256 + (size_t)chk * 1024;
        if (off > limit) off = limit;     // tail: dup last chunk (store-masked)
        __builtin_amdgcn_global_load_lds(
            (const __attribute__((address_space(1))) void*)(Gb + off + (size_t)lane * 16),
            (__attribute__((address_space(3))) void*)(xs + wv * 8192 + chk * 1024),
            16, 0, 0);
    }
    asm volatile("s_waitcnt vmcnt(0)" ::: "memory");
    __builtin_amdgcn_sched_barrier(0);

    const int c4 = (lane & 15) * 4;   // output channel base (0..60)
    const int rs = lane >> 4;         // row sub (0..3)

    float4 acc[8];
#pragma unroll
    for (int r = 0; r < 8; ++r) acc[r] = make_float4(0.f, 0.f, 0.f, 0.f);

#pragma unroll 2
    for (int k4 = 0; k4 < IN_C / 4; ++k4) {
        float4 xv[8];
#pragma unroll
        for (int r = 0; r < 8; ++r) {
            int rl = rs + r * 4;
            uint2 u = *reinterpret_cast<const uint2*>(
                &xs[wv * 8192 + rl * 256 + k4 * 8]);
            xv[r].x = bflo(u.x); xv[r].y = bfhi(u.x);
            xv[r].z = bflo(u.y); xv[r].w = bfhi(u.y);
        }
        float4 w0 = *reinterpret_cast<const float4*>(W + (size_t)(4 * k4 + 0) * OUT_C + c4);
        float4 w1 = *reinterpret_cast<const float4*>(W + (size_t)(4 * k4 + 1) * OUT_C + c4);
        float4 w2 = *reinterpret_cast<const float4*>(W + (size_t)(4 * k4 + 2) * OUT_C + c4);
        float4 w3 = *reinterpret_cast<const float4*>(W + (size_t)(4 * k4 + 3) * OUT_C + c4);
#pragma unroll
        for (int r = 0; r < 8; ++r) {
            acc[r].x = fmaf(xv[r].x, w0.x, acc[r].x);
            acc[r].y = fmaf(xv[r].x, w0.y, acc[r].y);
            acc[r].z = fmaf(xv[r].x, w0.z, acc[r].z);
            acc[r].w = fmaf(xv[r].x, w0.w, acc[r].w);
            acc[r].x = fmaf(xv[r].y, w1.x, acc[r].x);
            acc[r].y = fmaf(xv[r].y, w1.y, acc[r].y);
            acc[r].z = fmaf(xv[r].y, w1.z, acc[r].z);
            acc[r].w = fmaf(xv[r].y, w1.w, acc[r].w);
            acc[r].x = fmaf(xv[r].z, w2.x, acc[r].x);
            acc[r].y = fmaf(xv[r].z, w2.y, acc[r].y);
            acc[r].z = fmaf(xv[r].z, w2.z, acc[r].z);
            acc[r].w = fmaf(xv[r].z, w2.w, acc[r].w);
            acc[r].x = fmaf(xv[r].w, w3.x, acc[r].x);
            acc[r].y = fmaf(xv[r].w, w3.y, acc[r].y);
            acc[r].z = fmaf(xv[r].w, w3.z, acc[r].z);
            acc[r].w = fmaf(xv[r].w, w3.w, acc[r].w);
        }
    }

#pragma unroll
    for (int r = 0; r < 8; ++r) {
        int row = row0 + rs + r * 4;
        if (row < N_NODES) {
            ushort4 o;
            o.x = f2bf(acc[r].x);
            o.y = f2bf(acc[r].y);
            o.z = f2bf(acc[r].z);
            o.w = f2bf(acc[r].w);
            *reinterpret_cast<ushort4*>(outp + (size_t)row * OUT_C + c4) = o;
        }
    }
}

// ---------------------------------------------------------------------------
// Gather aggregation, FOUR nodes per wave (16 lanes each): one gather
// instruction covers 4 edges. Lane loads uint4 (C=128: full 256 B row) or
// uint2 (C=64: 128 B row). Divergent per-quarter loop bounds ride the exec
// mask; 8 gathers in flight.
// MODE 0: g[n] = dinv_n*relu(dinv_n*(sum+q[n]) + b1) -> bf16 [N][128]
// MODE 1: m = dinv_n*(sum+p[n]) + bmu; mu=logstd=m; zeta=m+eps*e^m
// ---------------------------------------------------------------------------
template <int C, int MODE>
__global__ void k_agg(const u16* __restrict__ sorted_src,
                      const u8* __restrict__ cnt8,
                      const float* __restrict__ dinv,
                      const u16* __restrict__ rows,     // bf16 rows
                      const float* __restrict__ bias,
                      const float* __restrict__ eps,
                      void* __restrict__ outbuf) {
    const int wave = threadIdx.x >> 6;
    const int q    = (threadIdx.x >> 4) & 3;   // quarter = node within wave
    const int ql   = threadIdx.x & 15;
    const int n = blockIdx.x * 16 + wave * 4 + q;
    if (n >= N_NODES) return;

    const int c = cnt8[n];
    const u16* bk = sorted_src + ((size_t)n << 6);
    const float di = dinv[n];

    if (C == 128) {
        const uint4* rw = reinterpret_cast<const uint4*>(rows);   // row = 16 uint4
        float a[8] = {0,0,0,0,0,0,0,0};
        float b[8] = {0,0,0,0,0,0,0,0};
        int j = 0;
        for (; j + 8 <= c; j += 8) {        // 8 row-gathers in flight per quarter
            ushort4 sa = *reinterpret_cast<const ushort4*>(bk + j);
            ushort4 sb = *reinterpret_cast<const ushort4*>(bk + j + 4);
            uint4 p0 = rw[(size_t)sa.x * 16 + ql];
            uint4 p1 = rw[(size_t)sa.y * 16 + ql];
            uint4 p2 = rw[(size_t)sa.z * 16 + ql];
            uint4 p3 = rw[(size_t)sa.w * 16 + ql];
            uint4 p4 = rw[(size_t)sb.x * 16 + ql];
            uint4 p5 = rw[(size_t)sb.y * 16 + ql];
            uint4 p6 = rw[(size_t)sb.z * 16 + ql];
            uint4 p7 = rw[(size_t)sb.w * 16 + ql];
            acc8(a, p0); acc8(b, p1); acc8(a, p2); acc8(b, p3);
            acc8(a, p4); acc8(b, p5); acc8(a, p6); acc8(b, p7);
        }
        for (; j + 4 <= c; j += 4) {
            ushort4 sa = *reinterpret_cast<const ushort4*>(bk + j);
            uint4 p0 = rw[(size_t)sa.x * 16 + ql];
            uint4 p1 = rw[(size_t)sa.y * 16 + ql];
            uint4 p2 = rw[(size_t)sa.z * 16 + ql];
            uint4 p3 = rw[(size_t)sa.w * 16 + ql];
            acc8(a, p0); acc8(b, p1); acc8(a, p2); acc8(b, p3);
        }
        for (; j < c; ++j)
            acc8(a, rw[(size_t)bk[j] * 16 + ql]);

        uint4 qn = rw[(size_t)n * 16 + ql];
        float s[8];
        s[0] = a[0] + b[0] + bflo(qn.x); s[1] = a[1] + b[1] + bfhi(qn.x);
        s[2] = a[2] + b[2] + bflo(qn.y); s[3] = a[3] + b[3] + bfhi(qn.y);
        s[4] = a[4] + b[4] + bflo(qn.z); s[5] = a[5] + b[5] + bfhi(qn.z);
        s[6] = a[6] + b[6] + bflo(qn.w); s[7] = a[7] + b[7] + bfhi(qn.w);
        const int ch = ql * 8;
        float4 bs0 = *reinterpret_cast<const float4*>(bias + ch);
        float4 bs1 = *reinterpret_cast<const float4*>(bias + ch + 4);
        float g0 = di * fmaxf(fmaf(di, s[0], bs0.x), 0.f);
        float g1 = di * fmaxf(fmaf(di, s[1], bs0.y), 0.f);
        float g2 = di * fmaxf(fmaf(di, s[2], bs0.z), 0.f);
        float g3 = di * fmaxf(fmaf(di, s[3], bs0.w), 0.f);
        float g4 = di * fmaxf(fmaf(di, s[4], bs1.x), 0.f);
        float g5 = di * fmaxf(fmaf(di, s[5], bs1.y), 0.f);
        float g6 = di * fmaxf(fmaf(di, s[6], bs1.z), 0.f);
        float g7 = di * fmaxf(fmaf(di, s[7], bs1.w), 0.f);
        uint4 o;
        o.x = (u32)f2bf(g0) | ((u32)f2bf(g1) << 16);
        o.y = (u32)f2bf(g2) | ((u32)f2bf(g3) << 16);
        o.z = (u32)f2bf(g4) | ((u32)f2bf(g5) << 16);
        o.w = (u32)f2bf(g6) | ((u32)f2bf(g7) << 16);
        reinterpret_cast<uint4*>(outbuf)[(size_t)n * 16 + ql] = o;
    } else {
        const uint2* rw = reinterpret_cast<const uint2*>(rows);   // row = 16 uint2
        float a[4] = {0,0,0,0};
        float b[4] = {0,0,0,0};
        int j = 0;
        for (; j + 8 <= c; j += 8) {
            ushort4 sa = *reinterpret_cast<const ushort4*>(bk + j);
            ushort4 sb = *reinterpret_cast<const ushort4*>(bk + j + 4);
            uint2 p0 = rw[(size_t)sa.x * 16 + ql];
            uint2 p1 = rw[(size_t)sa.y * 16 + ql];
            uint2 p2 = rw[(size_t)sa.z * 16 + ql];
            uint2 p3 = rw[(size_t)sa.w * 16 + ql];
            uint2 p4 = rw[(size_t)sb.x * 16 + ql];
            uint2 p5 = rw[(size_t)sb.y * 16 + ql];
            uint2 p6 = rw[(size_t)sb.z * 16 + ql];
            uint2 p7 = rw[(size_t)sb.w * 16 + ql];
            acc4(a, p0); acc4(b, p1); acc4(a, p2); acc4(b, p3);
            acc4(a, p4); acc4(b, p5); acc4(a, p6); acc4(b, p7);
        }
        for (; j + 4 <= c; j += 4) {
            ushort4 sa = *reinterpret_cast<const ushort4*>(bk + j);
            uint2 p0 = rw[(size_t)sa.x * 16 + ql];
            uint2 p1 = rw[(size_t)sa.y * 16 + ql];
            uint2 p2 = rw[(size_t)sa.z * 16 + ql];
            uint2 p3 = rw[(size_t)sa.w * 16 + ql];
            acc4(a, p0); acc4(b, p1); acc4(a, p2); acc4(b, p3);
        }
        for (; j < c; ++j)
            acc4(a, rw[(size_t)bk[j] * 16 + ql]);

        uint2 pn = rw[(size_t)n * 16 + ql];
        float s0 = a[0] + b[0] + bflo(pn.x);
        float s1 = a[1] + b[1] + bfhi(pn.x);
        float s2 = a[2] + b[2] + bflo(pn.y);
        float s3 = a[3] + b[3] + bfhi(pn.y);
        const int ch = ql * 4;
        float4 bs = *reinterpret_cast<const float4*>(bias + ch);
        float m0 = fmaf(di, s0, bs.x);
        float m1 = fmaf(di, s1, bs.y);
        float m2 = fmaf(di, s2, bs.z);
        float m3 = fmaf(di, s3, bs.w);
        const int NM = N_NODES * OUT_C;
        int i = n * 64 + ch;
        float4 e = *reinterpret_cast<const float4*>(eps + i);
        float4 mv = make_float4(m0, m1, m2, m3);
        float4 zv;
        zv.x = fmaf(e.x, expf(m0), m0);
        zv.y = fmaf(e.y, expf(m1), m1);
        zv.z = fmaf(e.z, expf(m2), m2);
        zv.w = fmaf(e.w, expf(m3), m3);
        float* o = (float*)outbuf;
        *reinterpret_cast<float4*>(o + i)          = mv;   // mu
        *reinterpret_cast<float4*>(o + NM + i)     = mv;   // logstd (ref bug)
        *reinterpret_cast<float4*>(o + 2 * NM + i) = zv;   // zeta
    }
}

// ---------------------------------------------------------------------------
extern "C" void kernel_launch(void* const* d_in, const int* in_sizes, int n_in,
                              void* d_out, int out_size, void* d_ws, size_t ws_size,
                              hipStream_t stream) {
    const float* x   = (const float*)d_in[0];
    const int*   ei  = (const int*)d_in[1];
    const float* W1  = (const float*)d_in[2];
    const float* b1  = (const float*)d_in[3];
    const float* Wmu = (const float*)d_in[4];
    const float* bmu = (const float*)d_in[5];
    // d_in[6]=Wls, d_in[7]=bls unused (reference bug reuses Wmu/bmu)
    const float* eps = (const float*)d_in[8];
    float* out = (float*)d_out;

    // workspace layout (16B-aligned slices), ~35.5 MB total (R15-proven):
    char* p = (char*)d_ws;
    int*  flag   = (int*)p;                        p += 16;
    int*  cursor = (int*)p;                        p += (size_t)N_NODES * CSTRIDE * 4;   // 3.2 MB
    float* dinv  = (float*)p;                      p += ((size_t)N_NODES * 4 + 15) / 16 * 16;
    u8*  cnt8    = (u8*)p;                         p += ((size_t)N_NODES + 15) / 16 * 16;
    u16* wbf     = (u16*)p;                        p += (size_t)IN_C * H_C * 2;          // 32 KB
    u16* sorted  = (u16*)p;                        p += ((size_t)N_NODES * BCAP * 2 + 15) / 16 * 16;
    u16* bufA    = (u16*)p;                        p += ((size_t)N_NODES * H_C * 2 + 15) / 16 * 16;
    u16* bufG    = (u16*)p;                        // g [N][128] bf16 = 12.8 MB
    u16* bufP    = bufA;                           // p [N][64] aliases q (dead)
    // src16/dst16 alias bufG: live only from k_pre through k_sort,
    // strictly before agg1 writes g there.
    u16* src16   = bufG;
    u16* dst16   = bufG + (size_t)N_EDGES;

    k_detect_i64<<<1, 64, 0, stream>>>(ei, flag);
    k_pre<<<(N_EDGES + 255) / 256, 256, 0, stream>>>(ei, flag, W1, wbf,
                                                     (int4*)cursor, src16, dst16);
    k_sort<<<8 * ((N_EDGES + EPB - 1) / EPB), 256, 0, stream>>>(dst16, src16, cursor, sorted);
    k_dinv<<<(N_NODES + 255) / 256, 256, 0, stream>>>(cursor, dinv, cnt8);

    // conv1: q = dinv .* (x @ W1) -> bufA (bf16 row-major), W bf16 via L1
    k_gemm1<<<(N_NODES + 63) / 64, 256, 0, stream>>>(x, wbf, dinv, bufA);
    // g = dinv .* relu(dinv.*(agg(q)+q) + b1) -> bufG (bf16 row-major)
    k_agg<H_C, 0><<<(N_NODES + 15) / 16, 256, 0, stream>>>(sorted, cnt8, dinv, bufA, b1, nullptr, bufG);
    // conv2: p = g @ Wmu -> bufP (bf16 row-major)
    k_gemm2<<<(N_NODES + 127) / 128, 256, 0, stream>>>(bufG, Wmu, bufP);
    // mu/logstd/zeta epilogue fused into aggregation
    k_agg<OUT_C, 1><<<(N_NODES + 15) / 16, 256, 0, stream>>>(sorted, cnt8, dinv, bufP, bmu, eps, out);
}

// Round 21
// 169.512 us; speedup vs baseline: 1.0246x; 1.0246x over previous
//
#include <hip/hip_runtime.h>
#include <math.h>

#define N_NODES 50000
#define N_EDGES 800000
#define IN_C    128
#define H_C     128
#define OUT_C   64
#define BCAP    64          // fixed bucket capacity (P(deg>64) ~ 1e-17 for Poisson(16))
#define EPB     2048        // edges per sort chunk
#define CSTRIDE 16          // cursor padded to one 64 B line per node (sort atomics)

typedef unsigned char  u8;
typedef unsigned short u16;
typedef unsigned int   u32;

// bf16 helpers (RNE)
__device__ __forceinline__ u16 f2bf(float f) {
    u32 u; __builtin_memcpy(&u, &f, 4);
    u += 0x7FFFu + ((u >> 16) & 1u);
    return (u16)(u >> 16);
}
__device__ __forceinline__ float bflo(u32 p) { u32 u = p << 16;         float f; __builtin_memcpy(&f, &u, 4); return f; }
__device__ __forceinline__ float bfhi(u32 p) { u32 u = p & 0xFFFF0000u; float f; __builtin_memcpy(&f, &u, 4); return f; }

// decode uint4 = 8 bf16 and accumulate into a[0..7]
__device__ __forceinline__ void acc8(float* a, uint4 p) {
    a[0] += bflo(p.x); a[1] += bfhi(p.x);
    a[2] += bflo(p.y); a[3] += bfhi(p.y);
    a[4] += bflo(p.z); a[5] += bfhi(p.z);
    a[6] += bflo(p.w); a[7] += bfhi(p.w);
}
// decode uint2 = 4 bf16 and accumulate into a[0..3]
__device__ __forceinline__ void acc4(float* a, uint2 p) {
    a[0] += bflo(p.x); a[1] += bfhi(p.x);
    a[2] += bflo(p.y); a[3] += bfhi(p.y);
}

// ---------------------------------------------------------------------------
// edge_index dtype detection (wave-parallel): int64 buffers have all odd
// int32 words == 0 (values < 50000). flag: 1 = int64, 0 = int32.
// ---------------------------------------------------------------------------
__global__ void k_detect_i64(const int* __restrict__ ei, int* __restrict__ flag) {
    int t = threadIdx.x;
    int nz = 0;
    for (int i = t; i < 256; i += 64)
        if (ei[2 * i + 1] != 0) nz = 1;
    unsigned long long b = __ballot(nz != 0);
    if (t == 0) *flag = (b == 0ULL) ? 1 : 0;
}

__device__ __forceinline__ int eidx(const int* __restrict__ ei, size_t pos, int mode) {
    return mode ? ei[pos << 1] : ei[pos];
}

// ---------------------------------------------------------------------------
// merged preprocessing (one 800K-thread kernel):
//   i < 200000: zero the line-padded cursor (int4)
//   i < 16384 : W1 fp32 -> bf16 (32 KB)
//   i < 800000: compact edge list to u16 (L2-resident for the 8 sort passes)
// ---------------------------------------------------------------------------
__global__ void k_pre(const int* __restrict__ ei, const int* __restrict__ flag,
                      const float* __restrict__ W, u16* __restrict__ Wbf,
                      int4* __restrict__ cursor4,
                      u16* __restrict__ src16, u16* __restrict__ dst16) {
    int i = blockIdx.x * 256 + threadIdx.x;
    if (i < N_NODES * CSTRIDE / 4) cursor4[i] = make_int4(0, 0, 0, 0);
    if (i < IN_C * H_C) Wbf[i] = f2bf(W[i]);
    if (i < N_EDGES) {
        int m = *flag;
        src16[i] = (u16)eidx(ei, (size_t)i, m);
        dst16[i] = (u16)eidx(ei, (size_t)N_EDGES + i, m);
    }
}

// ---------------------------------------------------------------------------
// XCD-partitioned bucket sort over compact u16 edges. Blocks (blockIdx&7)==p
// bin only edges with (dst&7)==p: bucket lines and (line-padded) cursor lines
// are each written by exactly one XCD.
// ---------------------------------------------------------------------------
__global__ void k_sort(const u16* __restrict__ dst16, const u16* __restrict__ src16,
                       int* __restrict__ cursor, u16* __restrict__ sorted_src) {
    const int part = blockIdx.x & 7;
    const int base = (blockIdx.x >> 3) * EPB;
    for (int i = threadIdx.x; i < EPB; i += 256) {
        int e = base + i;
        if (e >= N_EDGES) break;
        int d = dst16[e];
        if ((d & 7) != part) continue;
        int c = atomicAdd(&cursor[(size_t)d << 4], 1);
        if (c < BCAP) sorted_src[((size_t)d << 6) + c] = src16[e];
    }
}

// dinv from counts + dense u8 count array (50 KB, cache-resident for aggs)
__global__ void k_dinv(const int* __restrict__ cursor, float* __restrict__ dinv,
                       u8* __restrict__ cnt8) {
    int i = blockIdx.x * blockDim.x + threadIdx.x;
    if (i < N_NODES) {
        int c = cursor[(size_t)i << 4];
        dinv[i] = rsqrtf((float)c + 1.0f);
        cnt8[i] = (u8)(c > BCAP ? BCAP : c);
    }
}

// ---------------------------------------------------------------------------
// GEMM1: q = dinv .* (x @ W1), fp32 [N][128] -> bf16 row-major [N][128].
// 32-row tiles, 48 KB LDS (16 KB X fp32 + 32 KB W bf16), 256 threads ->
// 3 blocks/CU resident, grid 1563 (6.1/CU): resident blocks destagger their
// stage->barrier->compute phases (R19's 64-row 2-block version had the same
// zero-global-load k-loop but only 2 residents -> 35 us; R20's L1-W 782-grid
// was grid-limited at 19.7% occupancy -> 40 us). W re-stage per block is
// 50 MB chip-wide from hot L2/L3 (~1.5 us).
// ---------------------------------------------------------------------------
__launch_bounds__(256, 3)
__global__ void k_gemm1(const float* __restrict__ X, const u16* __restrict__ Wbf,
                        const float* __restrict__ dinv, u16* __restrict__ outq) {
    __shared__ __align__(16) char lds[49152];   // [0,16K) X fp32, [16K,48K) W bf16
    const int tid = threadIdx.x, wv = tid >> 6, lane = tid & 63;
    const int row0 = blockIdx.x * 32;
    const size_t limit = (size_t)N_NODES * 512 - 1024;   // last full 1 KB of x
    const char* Xb = (const char*)X;
    const char* Wb = (const char*)Wbf;

#pragma unroll
    for (int i = 0; i < 4; ++i) {               // X: 16 chunks, wave stages 4
        int chk = wv * 4 + i;
        size_t off = (size_t)row0 * 512 + (size_t)chk * 1024;
        if (off > limit) off = limit;           // tail: dup last chunk (store-masked)
        __builtin_amdgcn_global_load_lds(
            (const __attribute__((address_space(1))) void*)(Xb + off + (size_t)lane * 16),
            (__attribute__((address_space(3))) void*)(lds + chk * 1024),
            16, 0, 0);
    }
#pragma unroll
    for (int i = 0; i < 8; ++i) {               // W: 32 chunks, wave stages 8
        int wc = wv * 8 + i;
        __builtin_amdgcn_global_load_lds(
            (const __attribute__((address_space(1))) void*)(Wb + (size_t)wc * 1024 + (size_t)lane * 16),
            (__attribute__((address_space(3))) void*)(lds + 16384 + wc * 1024),
            16, 0, 0);
    }
    asm volatile("s_waitcnt vmcnt(0)" ::: "memory");
    __syncthreads();

    const int c4  = (tid & 31) * 4;   // output channel base (0..124)
    const int sub = tid >> 5;         // row subgroup (0..7)

    float4 acc[4];
#pragma unroll
    for (int r = 0; r < 4; ++r) acc[r] = make_float4(0.f, 0.f, 0.f, 0.f);

#pragma unroll 2
    for (int k4 = 0; k4 < IN_C / 4; ++k4) {
        float4 xv[4];
#pragma unroll
        for (int r = 0; r < 4; ++r)
            xv[r] = *reinterpret_cast<const float4*>(
                &lds[(sub + r * 8) * 512 + k4 * 16]);   // 32-thread broadcast (free)
        float4 w[4];
#pragma unroll
        for (int r = 0; r < 4; ++r) {
            uint2 wu = *reinterpret_cast<const uint2*>(
                &lds[16384 + (4 * k4 + r) * 256 + (tid & 31) * 8]);  // 2-way alias (free)
            w[r].x = bflo(wu.x); w[r].y = bfhi(wu.x);
            w[r].z = bflo(wu.y); w[r].w = bfhi(wu.y);
        }
#pragma unroll
        for (int r = 0; r < 4; ++r) {
            acc[r].x = fmaf(xv[r].x, w[0].x, acc[r].x);
            acc[r].y = fmaf(xv[r].x, w[0].y, acc[r].y);
            acc[r].z = fmaf(xv[r].x, w[0].z, acc[r].z);
            acc[r].w = fmaf(xv[r].x, w[0].w, acc[r].w);
            acc[r].x = fmaf(xv[r].y, w[1].x, acc[r].x);
            acc[r].y = fmaf(xv[r].y, w[1].y, acc[r].y);
            acc[r].z = fmaf(xv[r].y, w[1].z, acc[r].z);
            acc[r].w = fmaf(xv[r].y, w[1].w, acc[r].w);
            acc[r].x = fmaf(xv[r].z, w[2].x, acc[r].x);
            acc[r].y = fmaf(xv[r].z, w[2].y, acc[r].y);
            acc[r].z = fmaf(xv[r].z, w[2].z, acc[r].z);
            acc[r].w = fmaf(xv[r].z, w[2].w, acc[r].w);
            acc[r].x = fmaf(xv[r].w, w[3].x, acc[r].x);
            acc[r].y = fmaf(xv[r].w, w[3].y, acc[r].y);
            acc[r].z = fmaf(xv[r].w, w[3].z, acc[r].z);
            acc[r].w = fmaf(xv[r].w, w[3].w, acc[r].w);
        }
    }

#pragma unroll
    for (int r = 0; r < 4; ++r) {
        int row = row0 + sub + r * 8;
        if (row < N_NODES) {
            float di = dinv[row];
            ushort4 o;
            o.x = f2bf(acc[r].x * di);
            o.y = f2bf(acc[r].y * di);
            o.z = f2bf(acc[r].z * di);
            o.w = f2bf(acc[r].w * di);
            *reinterpret_cast<ushort4*>(outq + (size_t)row * H_C + c4) = o;
        }
    }
}

// ---------------------------------------------------------------------------
// GEMM2: p = g @ Wmu, bf16 row-major [N][128] -> bf16 row-major [N][64].
// Wave stages its 32 rows (8 KB bf16) independently; no __syncthreads.
// ---------------------------------------------------------------------------
__launch_bounds__(256, 4)
__global__ void k_gemm2(const u16* __restrict__ gbuf, const float* __restrict__ W,
                        u16* __restrict__ outp) {
    __shared__ __align__(16) char xs[32768];
    const int tid = threadIdx.x, wv = tid >> 6, lane = tid & 63;
    const int row0 = blockIdx.x * 128 + wv * 32;
    const size_t limit = (size_t)N_NODES * 256 - 1024;   // last full 1 KB of g
    const char* Gb = (const char*)gbuf;

#pragma unroll
    for (int chk = 0; chk < 8; ++chk) {
        size_t off = (size_t)row0 * 256 + (size_t)chk * 1024;
        if (off > limit) off = limit;     // tail: dup last chunk (store-masked)
        __builtin_amdgcn_global_load_lds(
            (const __attribute__((address_space(1))) void*)(Gb + off + (size_t)lane * 16),
            (__attribute__((address_space(3))) void*)(xs + wv * 8192 + chk * 1024),
            16, 0, 0);
    }
    asm volatile("s_waitcnt vmcnt(0)" ::: "memory");
    __builtin_amdgcn_sched_barrier(0);

    const int c4 = (lane & 15) * 4;   // output channel base (0..60)
    const int rs = lane >> 4;         // row sub (0..3)

    float4 acc[8];
#pragma unroll
    for (int r = 0; r < 8; ++r) acc[r] = make_float4(0.f, 0.f, 0.f, 0.f);

#pragma unroll 2
    for (int k4 = 0; k4 < IN_C / 4; ++k4) {
        float4 xv[8];
#pragma unroll
        for (int r = 0; r < 8; ++r) {
            int rl = rs + r * 4;
            uint2 u = *reinterpret_cast<const uint2*>(
                &xs[wv * 8192 + rl * 256 + k4 * 8]);
            xv[r].x = bflo(u.x); xv[r].y = bfhi(u.x);
            xv[r].z = bflo(u.y); xv[r].w = bfhi(u.y);
        }
        float4 w0 = *reinterpret_cast<const float4*>(W + (size_t)(4 * k4 + 0) * OUT_C + c4);
        float4 w1 = *reinterpret_cast<const float4*>(W + (size_t)(4 * k4 + 1) * OUT_C + c4);
        float4 w2 = *reinterpret_cast<const float4*>(W + (size_t)(4 * k4 + 2) * OUT_C + c4);
        float4 w3 = *reinterpret_cast<const float4*>(W + (size_t)(4 * k4 + 3) * OUT_C + c4);
#pragma unroll
        for (int r = 0; r < 8; ++r) {
            acc[r].x = fmaf(xv[r].x, w0.x, acc[r].x);
            acc[r].y = fmaf(xv[r].x, w0.y, acc[r].y);
            acc[r].z = fmaf(xv[r].x, w0.z, acc[r].z);
            acc[r].w = fmaf(xv[r].x, w0.w, acc[r].w);
            acc[r].x = fmaf(xv[r].y, w1.x, acc[r].x);
            acc[r].y = fmaf(xv[r].y, w1.y, acc[r].y);
            acc[r].z = fmaf(xv[r].y, w1.z, acc[r].z);
            acc[r].w = fmaf(xv[r].y, w1.w, acc[r].w);
            acc[r].x = fmaf(xv[r].z, w2.x, acc[r].x);
            acc[r].y = fmaf(xv[r].z, w2.y, acc[r].y);
            acc[r].z = fmaf(xv[r].z, w2.z, acc[r].z);
            acc[r].w = fmaf(xv[r].z, w2.w, acc[r].w);
            acc[r].x = fmaf(xv[r].w, w3.x, acc[r].x);
            acc[r].y = fmaf(xv[r].w, w3.y, acc[r].y);
            acc[r].z = fmaf(xv[r].w, w3.z, acc[r].z);
            acc[r].w = fmaf(xv[r].w, w3.w, acc[r].w);
        }
    }

#pragma unroll
    for (int r = 0; r < 8; ++r) {
        int row = row0 + rs + r * 4;
        if (row < N_NODES) {
            ushort4 o;
            o.x = f2bf(acc[r].x);
            o.y = f2bf(acc[r].y);
            o.z = f2bf(acc[r].z);
            o.w = f2bf(acc[r].w);
            *reinterpret_cast<ushort4*>(outp + (size_t)row * OUT_C + c4) = o;
        }
    }
}

// ---------------------------------------------------------------------------
// Gather aggregation, FOUR nodes per wave (16 lanes each): one gather
// instruction covers 4 edges. Lane loads uint4 (C=128: full 256 B row) or
// uint2 (C=64: 128 B row). Divergent per-quarter loop bounds ride the exec
// mask; 8 gathers in flight.
// MODE 0: g[n] = dinv_n*relu(dinv_n*(sum+q[n]) + b1) -> bf16 [N][128]
// MODE 1: m = dinv_n*(sum+p[n]) + bmu; mu=logstd=m; zeta=m+eps*e^m
// ---------------------------------------------------------------------------
template <int C, int MODE>
__global__ void k_agg(const u16* __restrict__ sorted_src,
                      const u8* __restrict__ cnt8,
                      const float* __restrict__ dinv,
                      const u16* __restrict__ rows,     // bf16 rows
                      const float* __restrict__ bias,
                      const float* __restrict__ eps,
                      void* __restrict__ outbuf) {
    const int wave = threadIdx.x >> 6;
    const int q    = (threadIdx.x >> 4) & 3;   // quarter = node within wave
    const int ql   = threadIdx.x & 15;
    const int n = blockIdx.x * 16 + wave * 4 + q;
    if (n >= N_NODES) return;

    const int c = cnt8[n];
    const u16* bk = sorted_src + ((size_t)n << 6);
    const float di = dinv[n];

    if (C == 128) {
        const uint4* rw = reinterpret_cast<const uint4*>(rows);   // row = 16 uint4
        float a[8] = {0,0,0,0,0,0,0,0};
        float b[8] = {0,0,0,0,0,0,0,0};
        int j = 0;
        for (; j + 8 <= c; j += 8) {        // 8 row-gathers in flight per quarter
            ushort4 sa = *reinterpret_cast<const ushort4*>(bk + j);
            ushort4 sb = *reinterpret_cast<const ushort4*>(bk + j + 4);
            uint4 p0 = rw[(size_t)sa.x * 16 + ql];
            uint4 p1 = rw[(size_t)sa.y * 16 + ql];
            uint4 p2 = rw[(size_t)sa.z * 16 + ql];
            uint4 p3 = rw[(size_t)sa.w * 16 + ql];
            uint4 p4 = rw[(size_t)sb.x * 16 + ql];
            uint4 p5 = rw[(size_t)sb.y * 16 + ql];
            uint4 p6 = rw[(size_t)sb.z * 16 + ql];
            uint4 p7 = rw[(size_t)sb.w * 16 + ql];
            acc8(a, p0); acc8(b, p1); acc8(a, p2); acc8(b, p3);
            acc8(a, p4); acc8(b, p5); acc8(a, p6); acc8(b, p7);
        }
        for (; j + 4 <= c; j += 4) {
            ushort4 sa = *reinterpret_cast<const ushort4*>(bk + j);
            uint4 p0 = rw[(size_t)sa.x * 16 + ql];
            uint4 p1 = rw[(size_t)sa.y * 16 + ql];
            uint4 p2 = rw[(size_t)sa.z * 16 + ql];
            uint4 p3 = rw[(size_t)sa.w * 16 + ql];
            acc8(a, p0); acc8(b, p1); acc8(a, p2); acc8(b, p3);
        }
        for (; j < c; ++j)
            acc8(a, rw[(size_t)bk[j] * 16 + ql]);

        uint4 qn = rw[(size_t)n * 16 + ql];
        float s[8];
        s[0] = a[0] + b[0] + bflo(qn.x); s[1] = a[1] + b[1] + bfhi(qn.x);
        s[2] = a[2] + b[2] + bflo(qn.y); s[3] = a[3] + b[3] + bfhi(qn.y);
        s[4] = a[4] + b[4] + bflo(qn.z); s[5] = a[5] + b[5] + bfhi(qn.z);
        s[6] = a[6] + b[6] + bflo(qn.w); s[7] = a[7] + b[7] + bfhi(qn.w);
        const int ch = ql * 8;
        float4 bs0 = *reinterpret_cast<const float4*>(bias + ch);
        float4 bs1 = *reinterpret_cast<const float4*>(bias + ch + 4);
        float g0 = di * fmaxf(fmaf(di, s[0], bs0.x), 0.f);
        float g1 = di * fmaxf(fmaf(di, s[1], bs0.y), 0.f);
        float g2 = di * fmaxf(fmaf(di, s[2], bs0.z), 0.f);
        float g3 = di * fmaxf(fmaf(di, s[3], bs0.w), 0.f);
        float g4 = di * fmaxf(fmaf(di, s[4], bs1.x), 0.f);
        float g5 = di * fmaxf(fmaf(di, s[5], bs1.y), 0.f);
        float g6 = di * fmaxf(fmaf(di, s[6], bs1.z), 0.f);
        float g7 = di * fmaxf(fmaf(di, s[7], bs1.w), 0.f);
        uint4 o;
        o.x = (u32)f2bf(g0) | ((u32)f2bf(g1) << 16);
        o.y = (u32)f2bf(g2) | ((u32)f2bf(g3) << 16);
        o.z = (u32)f2bf(g4) | ((u32)f2bf(g5) << 16);
        o.w = (u32)f2bf(g6) | ((u32)f2bf(g7) << 16);
        reinterpret_cast<uint4*>(outbuf)[(size_t)n * 16 + ql] = o;
    } else {
        const uint2* rw = reinterpret_cast<const uint2*>(rows);   // row = 16 uint2
        float a[4] = {0,0,0,0};
        float b[4] = {0,0,0,0};
        int j = 0;
        for (; j + 8 <= c; j += 8) {
            ushort4 sa = *reinterpret_cast<const ushort4*>(bk + j);
            ushort4 sb = *reinterpret_cast<const ushort4*>(bk + j + 4);
            uint2 p0 = rw[(size_t)sa.x * 16 + ql];
            uint2 p1 = rw[(size_t)sa.y * 16 + ql];
            uint2 p2 = rw[(size_t)sa.z * 16 + ql];
            uint2 p3 = rw[(size_t)sa.w * 16 + ql];
            uint2 p4 = rw[(size_t)sb.x * 16 + ql];
            uint2 p5 = rw[(size_t)sb.y * 16 + ql];
            uint2 p6 = rw[(size_t)sb.z * 16 + ql];
            uint2 p7 = rw[(size_t)sb.w * 16 + ql];
            acc4(a, p0); acc4(b, p1); acc4(a, p2); acc4(b, p3);
            acc4(a, p4); acc4(b, p5); acc4(a, p6); acc4(b, p7);
        }
        for (; j + 4 <= c; j += 4) {
            ushort4 sa = *reinterpret_cast<const ushort4*>(bk + j);
            uint2 p0 = rw[(size_t)sa.x * 16 + ql];
            uint2 p1 = rw[(size_t)sa.y * 16 + ql];
            uint2 p2 = rw[(size_t)sa.z * 16 + ql];
            uint2 p3 = rw[(size_t)sa.w * 16 + ql];
            acc4(a, p0); acc4(b, p1); acc4(a, p2); acc4(b, p3);
        }
        for (; j < c; ++j)
            acc4(a, rw[(size_t)bk[j] * 16 + ql]);

        uint2 pn = rw[(size_t)n * 16 + ql];
        float s0 = a[0] + b[0] + bflo(pn.x);
        float s1 = a[1] + b[1] + bfhi(pn.x);
        float s2 = a[2] + b[2] + bflo(pn.y);
        float s3 = a[3] + b[3] + bfhi(pn.y);
        const int ch = ql * 4;
        float4 bs = *reinterpret_cast<const float4*>(bias + ch);
        float m0 = fmaf(di, s0, bs.x);
        float m1 = fmaf(di, s1, bs.y);
        float m2 = fmaf(di, s2, bs.z);
        float m3 = fmaf(di, s3, bs.w);
        const int NM = N_NODES * OUT_C;
        int i = n * 64 + ch;
        float4 e = *reinterpret_cast<const float4*>(eps + i);
        float4 mv = make_float4(m0, m1, m2, m3);
        float4 zv;
        zv.x = fmaf(e.x, expf(m0), m0);
        zv.y = fmaf(e.y, expf(m1), m1);
        zv.z = fmaf(e.z, expf(m2), m2);
        zv.w = fmaf(e.w, expf(m3), m3);
        float* o = (float*)outbuf;
        *reinterpret_cast<float4*>(o + i)          = mv;   // mu
        *reinterpret_cast<float4*>(o + NM + i)     = mv;   // logstd (ref bug)
        *reinterpret_cast<float4*>(o + 2 * NM + i) = zv;   // zeta
    }
}

// ---------------------------------------------------------------------------
extern "C" void kernel_launch(void* const* d_in, const int* in_sizes, int n_in,
                              void* d_out, int out_size, void* d_ws, size_t ws_size,
                              hipStream_t stream) {
    const float* x   = (const float*)d_in[0];
    const int*   ei  = (const int*)d_in[1];
    const float* W1  = (const float*)d_in[2];
    const float* b1  = (const float*)d_in[3];
    const float* Wmu = (const float*)d_in[4];
    const float* bmu = (const float*)d_in[5];
    // d_in[6]=Wls, d_in[7]=bls unused (reference bug reuses Wmu/bmu)
    const float* eps = (const float*)d_in[8];
    float* out = (float*)d_out;

    // workspace layout (16B-aligned slices), ~35.5 MB total (R15-proven):
    char* p = (char*)d_ws;
    int*  flag   = (int*)p;                        p += 16;
    int*  cursor = (int*)p;                        p += (size_t)N_NODES * CSTRIDE * 4;   // 3.2 MB
    float* dinv  = (float*)p;                      p += ((size_t)N_NODES * 4 + 15) / 16 * 16;
    u8*  cnt8    = (u8*)p;                         p += ((size_t)N_NODES + 15) / 16 * 16;
    u16* wbf     = (u16*)p;                        p += (size_t)IN_C * H_C * 2;          // 32 KB
    u16* sorted  = (u16*)p;                        p += ((size_t)N_NODES * BCAP * 2 + 15) / 16 * 16;
    u16* bufA    = (u16*)p;                        p += ((size_t)N_NODES * H_C * 2 + 15) / 16 * 16;
    u16* bufG    = (u16*)p;                        // g [N][128] bf16 = 12.8 MB
    u16* bufP    = bufA;                           // p [N][64] aliases q (dead)
    // src16/dst16 alias bufG: live only from k_pre through k_sort,
    // strictly before agg1 writes g there.
    u16* src16   = bufG;
    u16* dst16   = bufG + (size_t)N_EDGES;

    k_detect_i64<<<1, 64, 0, stream>>>(ei, flag);
    k_pre<<<(N_EDGES + 255) / 256, 256, 0, stream>>>(ei, flag, W1, wbf,
                                                     (int4*)cursor, src16, dst16);
    k_sort<<<8 * ((N_EDGES + EPB - 1) / EPB), 256, 0, stream>>>(dst16, src16, cursor, sorted);
    k_dinv<<<(N_NODES + 255) / 256, 256, 0, stream>>>(cursor, dinv, cnt8);

    // conv1: q = dinv .* (x @ W1) -> bufA (bf16 row-major), X+W both in LDS
    k_gemm1<<<(N_NODES + 31) / 32, 256, 0, stream>>>(x, wbf, dinv, bufA);
    // g = dinv .* relu(dinv.*(agg(q)+q) + b1) -> bufG (bf16 row-major)
    k_agg<H_C, 0><<<(N_NODES + 15) / 16, 256, 0, stream>>>(sorted, cnt8, dinv, bufA, b1, nullptr, bufG);
    // conv2: p = g @ Wmu -> bufP (bf16 row-major)
    k_gemm2<<<(N_NODES + 127) / 128, 256, 0, stream>>>(bufG, Wmu, bufP);
    // mu/logstd/zeta epilogue fused into aggregation
    k_agg<OUT_C, 1><<<(N_NODES + 15) / 16, 256, 0, stream>>>(sorted, cnt8, dinv, bufP, bmu, eps, out);
}